// Round 11
// baseline (129.517 us; speedup 1.0000x reference)
//
#include <hip/hip_runtime.h>
#include <hip/hip_bf16.h>
#include <stdint.h>

typedef __bf16 bf16;
typedef __bf16 bf16x8 __attribute__((ext_vector_type(8)));
typedef __bf16 bf16x4 __attribute__((ext_vector_type(4)));
typedef __bf16 bf16x2 __attribute__((ext_vector_type(2)));
typedef float  f32x4  __attribute__((ext_vector_type(4)));
typedef float  f32x16 __attribute__((ext_vector_type(16)));
typedef int    i32x4  __attribute__((ext_vector_type(4)));

#define MFMA16(A, B, C) __builtin_amdgcn_mfma_f32_16x16x32_bf16((A), (B), (C), 0, 0, 0)
#define MFMA32(A, B, C) __builtin_amdgcn_mfma_f32_32x32x16_bf16((A), (B), (C), 0, 0, 0)

static constexpr int Bsz = 4, Seq = 2048, Dm = 512, Hh = 8, Dh = 64;

__device__ __forceinline__ void g2l_16(void* lds, const void* gp) {
  __builtin_amdgcn_global_load_lds((__attribute__((address_space(1))) void*)gp,
                                   (__attribute__((address_space(3))) void*)lds, 16, 0, 0);
}

__device__ __forceinline__ float max3f(float a, float b, float c) {
  return fmaxf(fmaxf(a, b), c);   // clang fuses to v_max3_f32
}

__device__ __forceinline__ int pk2(float x, float y) {
  bf16x2 t; t[0] = (bf16)x; t[1] = (bf16)y;   // compiler emits cvt_pk (m240: don't hand-asm)
  return __builtin_bit_cast(int, t);
}

// ---------------- LayerNorm fp32 -> bf16, one wave per row (D=512) ----------------
__global__ __launch_bounds__(256) void ln_cast_kernel(
    const float* __restrict__ x, const float* __restrict__ g,
    const float* __restrict__ be, bf16* __restrict__ xn) {
  const int row  = blockIdx.x * 4 + (threadIdx.x >> 6);
  const int lane = threadIdx.x & 63;
  const f32x4* xr = (const f32x4*)(x + (size_t)row * Dm);
  f32x4 v0 = xr[lane];
  f32x4 v1 = xr[lane + 64];
  float s = (v0.x + v0.y + v0.z + v0.w) + (v1.x + v1.y + v1.z + v1.w);
#pragma unroll
  for (int off = 32; off > 0; off >>= 1) s += __shfl_xor(s, off);
  const float mu = s * (1.0f / Dm);
  f32x4 d0 = v0 - mu, d1 = v1 - mu;
  float q = d0.x * d0.x + d0.y * d0.y + d0.z * d0.z + d0.w * d0.w
          + d1.x * d1.x + d1.y * d1.y + d1.z * d1.z + d1.w * d1.w;
#pragma unroll
  for (int off = 32; off > 0; off >>= 1) q += __shfl_xor(q, off);
  const float rs = rsqrtf(q * (1.0f / Dm) + 1e-5f);
  const f32x4* gr = (const f32x4*)g;
  const f32x4* br = (const f32x4*)be;
  f32x4 g0 = gr[lane], g1 = gr[lane + 64];
  f32x4 b0 = br[lane], b1 = br[lane + 64];
  f32x4 y0 = d0 * rs * g0 + b0;
  f32x4 y1 = d1 * rs * g1 + b1;
  bf16x4 o0 = { (bf16)y0.x, (bf16)y0.y, (bf16)y0.z, (bf16)y0.w };
  bf16x4 o1 = { (bf16)y1.x, (bf16)y1.y, (bf16)y1.z, (bf16)y1.w };
  bf16x4* orow = (bf16x4*)(xn + (size_t)row * Dm);
  orow[lane]      = o0;
  orow[lane + 64] = o1;
}

// ------- transpose + cast: src[R][C] f32 -> dst[C][R] bf16; rows < qrows get *qscale
__global__ __launch_bounds__(256) void tcast_kernel(
    const float* __restrict__ src, bf16* __restrict__ dst, int R, int C,
    int qrows, float qscale) {
  __shared__ float t[32][33];
  const int c0 = blockIdx.x * 32, r0 = blockIdx.y * 32;
  const int tx = threadIdx.x & 31, ty = threadIdx.x >> 5;
#pragma unroll
  for (int i = 0; i < 32; i += 8)
    t[ty + i][tx] = src[(size_t)(r0 + ty + i) * C + c0 + tx];
  __syncthreads();
#pragma unroll
  for (int i = 0; i < 32; i += 8) {
    const int rr = c0 + ty + i;
    const float sc = rr < qrows ? qscale : 1.0f;
    dst[(size_t)rr * R + r0 + tx] = (bf16)(t[tx][ty + i] * sc);
  }
}

// ---- QKV GEMM (dbuf prefetch): [8192,512]x[512,1536] -> Q/K [B,H,S,64], V^T -------
__global__ __launch_bounds__(256) void gemm_qkv_kernel(
    const bf16* __restrict__ A,   // [8192][512]
    const bf16* __restrict__ Bt,  // [1536][512]  (w_qkv transposed)
    bf16* __restrict__ Qb, bf16* __restrict__ Kb, bf16* __restrict__ VT) {
  constexpr int K = 512;
  __shared__ __align__(16) bf16 As[2][128 * 32];
  __shared__ __align__(16) bf16 Bs[2][128 * 32];
  const int m0 = blockIdx.x * 128, n0 = blockIdx.y * 128;
  const int tid = threadIdx.x, lane = tid & 63, wave = tid >> 6;
  const int lr = lane & 15, lg = lane >> 4;
  const int wm = (wave >> 1) * 64, wn = (wave & 1) * 64;
  const int srow = wave * 16 + (lane >> 2);
  const int scol = (lane & 3) * 8;
  const bf16* ga = A  + (size_t)(m0 + srow) * K + scol;
  const bf16* gb = Bt + (size_t)(n0 + srow) * K + scol;
  bf16* lA = &As[0][0] + wave * 512;
  bf16* lB = &Bs[0][0] + wave * 512;
  f32x4 acc[4][4] = {};

  auto STAGE = [&](int buf, int k0) {
    g2l_16(lA + buf * 4096,        ga + k0);
    g2l_16(lA + buf * 4096 + 2048, ga + (size_t)64 * K + k0);
    g2l_16(lB + buf * 4096,        gb + k0);
    g2l_16(lB + buf * 4096 + 2048, gb + (size_t)64 * K + k0);
  };
  auto COMPUTE = [&](int buf) {
    const bf16* as = &As[buf][0];
    const bf16* bs = &Bs[buf][0];
    bf16x8 af[4], bfr[4];
#pragma unroll
    for (int i = 0; i < 4; ++i)
      af[i] = *(const bf16x8*)&as[(wm + i * 16 + lr) * 32 + lg * 8];
#pragma unroll
    for (int j = 0; j < 4; ++j)
      bfr[j] = *(const bf16x8*)&bs[(wn + j * 16 + lr) * 32 + lg * 8];
#pragma unroll
    for (int i = 0; i < 4; ++i)
#pragma unroll
      for (int j = 0; j < 4; ++j)
        acc[i][j] = MFMA16(af[i], bfr[j], acc[i][j]);
  };

  STAGE(0, 0);
  asm volatile("s_waitcnt vmcnt(0)" ::: "memory");
  __syncthreads();
  for (int it = 0; it < 8; ++it) {
    STAGE(1, it * 64 + 32);                 // prefetch odd K-tile
    COMPUTE(0);
    asm volatile("s_waitcnt vmcnt(0)" ::: "memory");
    __syncthreads();
    if (it < 7) STAGE(0, it * 64 + 64);     // prefetch even K-tile
    COMPUTE(1);
    asm volatile("s_waitcnt vmcnt(0)" ::: "memory");
    __syncthreads();
  }
#pragma unroll
  for (int j = 0; j < 4; ++j) {
    const int n = n0 + wn + j * 16 + lr;
    const int which = n >> 9, h = (n >> 6) & 7, dh = n & 63;
    if (which < 2) {
      bf16* dst = which == 0 ? Qb : Kb;
#pragma unroll
      for (int i = 0; i < 4; ++i)
#pragma unroll
        for (int r = 0; r < 4; ++r) {
          const int m = m0 + wm + i * 16 + lg * 4 + r;
          const int b = m >> 11, s2 = m & 2047;
          dst[((size_t)((b * Hh + h) * Seq + s2) << 6) | dh] = (bf16)acc[i][j][r];
        }
    } else {
      // V: write transposed [bh][dh][s]
#pragma unroll
      for (int i = 0; i < 4; ++i)
#pragma unroll
        for (int r = 0; r < 4; ++r) {
          const int m = m0 + wm + i * 16 + lg * 4 + r;
          const int b = m >> 11, s2 = m & 2047;
          VT[((size_t)((b * Hh + h) * Dh + dh)) * Seq + s2] = (bf16)acc[i][j][r];
        }
    }
  }
}

// ---- Out GEMM (dbuf prefetch): [8192,512]x[512,512] + bias -> fp32 out ------------
__global__ __launch_bounds__(256) void gemm_out_kernel(
    const bf16* __restrict__ A,   // [8192][512] attention output
    const bf16* __restrict__ Bt,  // [512][512]  (w_out transposed)
    const float* __restrict__ bias, float* __restrict__ out) {
  constexpr int K = 512;
  __shared__ __align__(16) bf16 As[2][128 * 32];
  __shared__ __align__(16) bf16 Bs[2][128 * 32];
  const int m0 = blockIdx.x * 128, n0 = blockIdx.y * 128;
  const int tid = threadIdx.x, lane = tid & 63, wave = tid >> 6;
  const int lr = lane & 15, lg = lane >> 4;
  const int wm = (wave >> 1) * 64, wn = (wave & 1) * 64;
  const int srow = wave * 16 + (lane >> 2);
  const int scol = (lane & 3) * 8;
  const bf16* ga = A  + (size_t)(m0 + srow) * K + scol;
  const bf16* gb = Bt + (size_t)(n0 + srow) * K + scol;
  bf16* lA = &As[0][0] + wave * 512;
  bf16* lB = &Bs[0][0] + wave * 512;
  f32x4 acc[4][4] = {};

  auto STAGE = [&](int buf, int k0) {
    g2l_16(lA + buf * 4096,        ga + k0);
    g2l_16(lA + buf * 4096 + 2048, ga + (size_t)64 * K + k0);
    g2l_16(lB + buf * 4096,        gb + k0);
    g2l_16(lB + buf * 4096 + 2048, gb + (size_t)64 * K + k0);
  };
  auto COMPUTE = [&](int buf) {
    const bf16* as = &As[buf][0];
    const bf16* bs = &Bs[buf][0];
    bf16x8 af[4], bfr[4];
#pragma unroll
    for (int i = 0; i < 4; ++i)
      af[i] = *(const bf16x8*)&as[(wm + i * 16 + lr) * 32 + lg * 8];
#pragma unroll
    for (int j = 0; j < 4; ++j)
      bfr[j] = *(const bf16x8*)&bs[(wn + j * 16 + lr) * 32 + lg * 8];
#pragma unroll
    for (int i = 0; i < 4; ++i)
#pragma unroll
      for (int j = 0; j < 4; ++j)
        acc[i][j] = MFMA16(af[i], bfr[j], acc[i][j]);
  };

  STAGE(0, 0);
  asm volatile("s_waitcnt vmcnt(0)" ::: "memory");
  __syncthreads();
  for (int it = 0; it < 8; ++it) {
    STAGE(1, it * 64 + 32);
    COMPUTE(0);
    asm volatile("s_waitcnt vmcnt(0)" ::: "memory");
    __syncthreads();
    if (it < 7) STAGE(0, it * 64 + 64);
    COMPUTE(1);
    asm volatile("s_waitcnt vmcnt(0)" ::: "memory");
    __syncthreads();
  }
#pragma unroll
  for (int j = 0; j < 4; ++j) {
    const int n = n0 + wn + j * 16 + lr;
    const float bv = bias[n];
#pragma unroll
    for (int i = 0; i < 4; ++i)
#pragma unroll
      for (int r = 0; r < 4; ++r) {
        const int m = m0 + wm + i * 16 + lg * 4 + r;
        out[(size_t)m * 512 + n] = acc[i][j][r] + bv;
      }
  }
}

// ---- Flash attention v10: 32x32 swapped QK^T, P fully in-register (T12-shfl) ------
// 8 waves x 32 q = 256 q/block; KV-split 2 (1024 keys), KVBLK=64, 16 tiles.
// LDS = K/V dbuf only (32 KB). P C/D layout k=(r&3)+8(r>>2)+4h5 -> PV A-frags via
// 16 bf16-packs + 4 shfl_xor(32) + selects per slice (m214 v22, shfl variant).
// l via in-lane sum tree (no ones-MFMA, no 16-reg ol). Partials OPn + ML (m,l).
__global__ __launch_bounds__(512) void attn10_kernel(
    const bf16* __restrict__ Qb, const bf16* __restrict__ Kb,
    const bf16* __restrict__ VT, bf16* __restrict__ OPn, float2* __restrict__ ML) {
  // bijective XCD-chunked swizzle: 512 blocks -> 64/XCD -> 4 complete heads/XCD
  const int o   = blockIdx.x + gridDim.x * blockIdx.y;  // 0..511
  const int nid = ((o & 7) << 6) + (o >> 3);
  const int qs = nid & 15, bh = nid >> 4;
  const int qc = qs >> 1, sp = qs & 1;
  const int tid = threadIdx.x, lane = tid & 63, wave = tid >> 6;   // wave 0..7
  const int q_l = lane & 31, h5 = lane >> 5;
  const int kx  = q_l & 7;
  const int q0w = qc * 256 + wave * 32;
  const bf16* Qh = Qb + (size_t)bh * Seq * Dh;
  const bf16* Kh = Kb + (size_t)bh * Seq * Dh;
  const bf16* Vh = VT + (size_t)bh * Dh * Seq;

  // KV[buf]: [0,4096) = K tile 64x64 (swizzled), [4096,8192) = V^T tile 64x64
  __shared__ __align__(16) bf16 KV[2][8192];
  const bf16* kv = &KV[0][0];

  // staging: 512 threads x 16B = 8KB/round (K and V halves), attn9 pattern
  const int krow = tid >> 3;                       // 0..63
  const int kc   = (((tid & 7) ^ (krow & 7)) * 8); // pre-swizzled source col
  const bf16* gK = Kh + (size_t)(sp * 1024 + krow) * 64 + kc;  // + t*4096
  const bf16* gV = Vh + (size_t)krow * Seq + sp * 1024 + kc;   // + t*64
  bf16* ldsD = &KV[0][0] + tid * 8;

  auto STAGE = [&](int dstOff, int t) {
    g2l_16(ldsD + dstOff,        gK + (size_t)t * 4096);
    g2l_16(ldsD + dstOff + 4096, gV + t * 64);
  };

  // Q B-fragments: qfr[s][i] = Q'[q0w+q_l][16s + 8*h5 + i]  (exp2-scaled)
  bf16x8 qfr[4];
#pragma unroll
  for (int s = 0; s < 4; ++s)
    qfr[s] = *(const bf16x8*)&Qh[(size_t)(q0w + q_l) * 64 + 16 * s + 8 * h5];

  f32x16 oa0 = {}, oa1 = {};
  float m = -1e30f, ls = 0.0f;

  // P C/D -> PV A-frag: frag words [h5?sxC:A, h5?sxD:B, h5?C:sxA, h5?D:sxB]
  auto mkfrag = [&](float p0, float p1, float p2, float p3,
                    float p4, float p5, float p6, float p7) -> bf16x8 {
    const int A = pk2(p0, p1), B = pk2(p2, p3), C = pk2(p4, p5), D = pk2(p6, p7);
    const int sxA = __shfl_xor(A, 32), sxB = __shfl_xor(B, 32);
    const int sxC = __shfl_xor(C, 32), sxD = __shfl_xor(D, 32);
    i32x4 w = { h5 ? sxC : A, h5 ? sxD : B, h5 ? C : sxA, h5 ? D : sxB };
    return __builtin_bit_cast(bf16x8, w);
  };

  auto TILE = [&](int buf) {   // buf literal at each call site
    const int kB = buf * 8192;
    // S^T = K Q'^T : st0 = k rows 0..31, st1 = 32..63; lane holds col q=q_l
    f32x16 st0 = {}, st1 = {};
#pragma unroll
    for (int s = 0; s < 4; ++s) {
      const int eoff = ((2 * s + h5) ^ kx) << 3;
      bf16x8 kf0 = *(const bf16x8*)&kv[kB + q_l * 64 + eoff];
      bf16x8 kf1 = *(const bf16x8*)&kv[kB + (32 + q_l) * 64 + eoff];
      st0 = MFMA32(kf0, qfr[s], st0);
      st1 = MFMA32(kf1, qfr[s], st1);
    }
    // softmax: in-lane max over 32 + one cross-lane (lane^32 completes 64 k)
    float mx = max3f(st0[0], st0[1], st1[0]);
#pragma unroll
    for (int r = 1; r < 8; ++r) mx = max3f(st0[2 * r], st0[2 * r + 1], mx);
#pragma unroll
    for (int r = 0; r < 5; ++r) mx = max3f(st1[2 * r + 1], st1[2 * r + 2], mx);
    mx = max3f(st1[11], st1[12], mx);
    mx = max3f(st1[13], st1[14], mx);
    mx = fmaxf(st1[15], mx);
    mx = fmaxf(mx, __shfl_xor(mx, 32));
    if (__any(mx > m + 3.0f)) {            // defer-max THR=3 (exp2 domain)
      const float mn = fmaxf(m, mx);
      const float al = exp2f(m - mn);
      m = mn;
      ls *= al;
#pragma unroll
      for (int r = 0; r < 16; ++r) {
        const int qr = (r & 3) + 8 * (r >> 2) + 4 * h5;
        const float aj = __shfl(al, qr);
        oa0[r] *= aj; oa1[r] *= aj;
      }
    }
    // P = exp2(st - m) in place; l-sum via 4-accumulator tree + pair exchange
#pragma unroll
    for (int i = 0; i < 16; ++i) {
      st0[i] = exp2f(st0[i] - m);
      st1[i] = exp2f(st1[i] - m);
    }
    {
      float t0 = 0, t1 = 0, t2 = 0, t3 = 0;
#pragma unroll
      for (int i = 0; i < 4; ++i) {
        t0 += st0[i] + st0[i + 4];  t1 += st0[i + 8] + st0[i + 12];
        t2 += st1[i] + st1[i + 4];  t3 += st1[i + 8] + st1[i + 12];
      }
      float ps = (t0 + t1) + (t2 + t3);
      ps += __shfl_xor(ps, 32);
      ls += ps;
    }
    // PV A-fragments fully in-register (no P LDS)
    bf16x8 pa0 = mkfrag(st0[0], st0[1], st0[2],  st0[3],  st0[4],  st0[5],  st0[6],  st0[7]);
    bf16x8 pa1 = mkfrag(st0[8], st0[9], st0[10], st0[11], st0[12], st0[13], st0[14], st0[15]);
    bf16x8 pa2 = mkfrag(st1[0], st1[1], st1[2],  st1[3],  st1[4],  st1[5],  st1[6],  st1[7]);
    bf16x8 pa3 = mkfrag(st1[8], st1[9], st1[10], st1[11], st1[12], st1[13], st1[14], st1[15]);
    // PV: O[q][d] += P[q][k] V[k][d]
#pragma unroll
    for (int s = 0; s < 4; ++s) {
      const bf16x8 pa = s == 0 ? pa0 : s == 1 ? pa1 : s == 2 ? pa2 : pa3;
      const int eoff = ((2 * s + h5) ^ kx) << 3;
      bf16x8 vf0 = *(const bf16x8*)&kv[kB + 4096 + q_l * 64 + eoff];
      bf16x8 vf1 = *(const bf16x8*)&kv[kB + 4096 + (32 + q_l) * 64 + eoff];
      oa0 = MFMA32(pa, vf0, oa0);
      oa1 = MFMA32(pa, vf1, oa1);
    }
  };

  // prologue: stage tile 0 into buf0
  STAGE(0, 0);
  asm volatile("s_waitcnt vmcnt(0)" ::: "memory");
  __syncthreads();

  for (int it = 0; it < 8; ++it) {
    STAGE(8192, 2 * it + 1);                 // stage odd tile into buf1
    TILE(0);
    asm volatile("s_waitcnt vmcnt(0)" ::: "memory");
    __syncthreads();
    if (it < 7) STAGE(0, 2 * it + 2);        // stage even tile into buf0
    TILE(1);
    asm volatile("s_waitcnt vmcnt(0)" ::: "memory");
    __syncthreads();
  }

  // epilogue: normalized partial O + (m, l); row qr data via pair-uniform shfl
#pragma unroll
  for (int r = 0; r < 16; ++r) {
    const int qr = (r & 3) + 8 * (r >> 2) + 4 * h5;
    const float lr_ = __shfl(ls, qr);
    const float mj  = __shfl(m, qr);
    const float inv = 1.0f / lr_;
    const size_t row = (size_t)bh * Seq + q0w + qr;
    OPn[((size_t)sp << 22) + row * 64 + q_l]      = (bf16)(oa0[r] * inv);
    OPn[((size_t)sp << 22) + row * 64 + 32 + q_l] = (bf16)(oa1[r] * inv);
    if (lane == 0 || q_l == 0) {
      if (q_l == 0) ML[(sp << 16) + row] = make_float2(mj, lr_);
    }
  }
}

// ------- combine the two KV-split partials -> A2 [B*S, 512] bf16 ------------------
__global__ __launch_bounds__(256) void attn_combine_kernel(
    const bf16* __restrict__ OPn, const float2* __restrict__ ML,
    bf16* __restrict__ A2) {
  const int r = blockIdx.x * 4 + (threadIdx.x >> 6);   // q-row: bh*2048 + s
  const int d = threadIdx.x & 63;
  const float2 ml0 = ML[r];
  const float2 ml1 = ML[65536 + r];
  const float M  = fmaxf(ml0.x, ml1.x);
  const float a0 = exp2f(ml0.x - M) * ml0.y;
  const float a1 = exp2f(ml1.x - M) * ml1.y;
  const float inv = 1.0f / (a0 + a1);
  const float v0 = (float)OPn[(size_t)r * 64 + d];
  const float v1 = (float)OPn[(size_t)(1 << 22) + (size_t)r * 64 + d];
  const int bh = r >> 11, s = r & 2047;
  const int b = bh >> 3, h = bh & 7;
  A2[(size_t)(b * Seq + s) * 512 + h * 64 + d] = (bf16)((a0 * v0 + a1 * v1) * inv);
}

extern "C" void kernel_launch(void* const* d_in, const int* in_sizes, int n_in,
                              void* d_out, int out_size, void* d_ws, size_t ws_size,
                              hipStream_t stream) {
  const float* x    = (const float*)d_in[0];
  const float* gam  = (const float*)d_in[1];
  const float* bet  = (const float*)d_in[2];
  const float* wqkv = (const float*)d_in[3];  // [512][1536]
  const float* wout = (const float*)d_in[4];  // [512][512]
  const float* bout = (const float*)d_in[5];  // [512]
  float* out = (float*)d_out;

  bf16* xn    = (bf16*)d_ws;                        // [8192][512]   8 MB
  bf16* wqkvT = xn    + (size_t)8192 * 512;         // [1536][512]   1.5 MB
  bf16* woutT = wqkvT + (size_t)1536 * 512;         // [512][512]    0.5 MB
  bf16* Qb    = woutT + (size_t)512 * 512;          // [4,8,2048,64] 8 MB
  bf16* Kb    = Qb    + (size_t)4 * 8 * 2048 * 64;
  bf16* VT    = Kb    + (size_t)4 * 8 * 2048 * 64;  // [4,8,64,2048] 8 MB
  bf16* OPn   = VT    + (size_t)4 * 8 * 2048 * 64;  // [2][65536][64] bf16  16.8 MB
  float2* ML  = (float2*)(OPn + ((size_t)2 << 22)); // [2][65536]           1 MB
  bf16* A2    = xn;  // reuse: xn dead after QKV GEMM

  // 64^-0.5 * log2(e) folded into Q columns of w_qkv
  const float K1 = 0.18033688011112042f;

  ln_cast_kernel<<<2048, 256, 0, stream>>>(x, gam, bet, xn);
  tcast_kernel<<<dim3(48, 16), 256, 0, stream>>>(wqkv, wqkvT, 512, 1536, 512, K1);
  tcast_kernel<<<dim3(16, 16), 256, 0, stream>>>(wout, woutT, 512, 512, 0, 1.0f);
  gemm_qkv_kernel<<<dim3(64, 12), 256, 0, stream>>>(xn, wqkvT, Qb, Kb, VT);
  attn10_kernel<<<dim3(16, 32), 512, 0, stream>>>(Qb, Kb, VT, OPn, ML);
  attn_combine_kernel<<<16384, 256, 0, stream>>>(OPn, ML, A2);
  gemm_out_kernel<<<dim3(64, 4), 256, 0, stream>>>(A2, woutT, bout, out);
}

// Round 13
// 110.176 us; speedup vs baseline: 1.1755x; 1.1755x over previous
//
#include <hip/hip_runtime.h>
#include <hip/hip_bf16.h>
#include <stdint.h>

typedef __bf16 bf16;
typedef __bf16 bf16x8 __attribute__((ext_vector_type(8)));
typedef __bf16 bf16x4 __attribute__((ext_vector_type(4)));
typedef float  f32x4  __attribute__((ext_vector_type(4)));

#define MFMA16(A, B, C) __builtin_amdgcn_mfma_f32_16x16x32_bf16((A), (B), (C), 0, 0, 0)

static constexpr int Bsz = 4, Seq = 2048, Dm = 512, Hh = 8, Dh = 64;

__device__ __forceinline__ void g2l_16(void* lds, const void* gp) {
  __builtin_amdgcn_global_load_lds((__attribute__((address_space(1))) void*)gp,
                                   (__attribute__((address_space(3))) void*)lds, 16, 0, 0);
}

__device__ __forceinline__ float max3f(float a, float b, float c) {
  return fmaxf(fmaxf(a, b), c);   // clang fuses to v_max3_f32
}

// ---------------- LayerNorm fp32 -> bf16, one wave per row (D=512) ----------------
__global__ __launch_bounds__(256) void ln_cast_kernel(
    const float* __restrict__ x, const float* __restrict__ g,
    const float* __restrict__ be, bf16* __restrict__ xn) {
  const int row  = blockIdx.x * 4 + (threadIdx.x >> 6);
  const int lane = threadIdx.x & 63;
  const f32x4* xr = (const f32x4*)(x + (size_t)row * Dm);
  f32x4 v0 = xr[lane];
  f32x4 v1 = xr[lane + 64];
  float s = (v0.x + v0.y + v0.z + v0.w) + (v1.x + v1.y + v1.z + v1.w);
#pragma unroll
  for (int off = 32; off > 0; off >>= 1) s += __shfl_xor(s, off);
  const float mu = s * (1.0f / Dm);
  f32x4 d0 = v0 - mu, d1 = v1 - mu;
  float q = d0.x * d0.x + d0.y * d0.y + d0.z * d0.z + d0.w * d0.w
          + d1.x * d1.x + d1.y * d1.y + d1.z * d1.z + d1.w * d1.w;
#pragma unroll
  for (int off = 32; off > 0; off >>= 1) q += __shfl_xor(q, off);
  const float rs = rsqrtf(q * (1.0f / Dm) + 1e-5f);
  const f32x4* gr = (const f32x4*)g;
  const f32x4* br = (const f32x4*)be;
  f32x4 g0 = gr[lane], g1 = gr[lane + 64];
  f32x4 b0 = br[lane], b1 = br[lane + 64];
  f32x4 y0 = d0 * rs * g0 + b0;
  f32x4 y1 = d1 * rs * g1 + b1;
  bf16x4 o0 = { (bf16)y0.x, (bf16)y0.y, (bf16)y0.z, (bf16)y0.w };
  bf16x4 o1 = { (bf16)y1.x, (bf16)y1.y, (bf16)y1.z, (bf16)y1.w };
  bf16x4* orow = (bf16x4*)(xn + (size_t)row * Dm);
  orow[lane]      = o0;
  orow[lane + 64] = o1;
}

// ------- transpose + cast: src[R][C] f32 -> dst[C][R] bf16; rows < qrows get *qscale
__global__ __launch_bounds__(256) void tcast_kernel(
    const float* __restrict__ src, bf16* __restrict__ dst, int R, int C,
    int qrows, float qscale) {
  __shared__ float t[32][33];
  const int c0 = blockIdx.x * 32, r0 = blockIdx.y * 32;
  const int tx = threadIdx.x & 31, ty = threadIdx.x >> 5;
#pragma unroll
  for (int i = 0; i < 32; i += 8)
    t[ty + i][tx] = src[(size_t)(r0 + ty + i) * C + c0 + tx];
  __syncthreads();
#pragma unroll
  for (int i = 0; i < 32; i += 8) {
    const int rr = c0 + ty + i;
    const float sc = rr < qrows ? qscale : 1.0f;
    dst[(size_t)rr * R + r0 + tx] = (bf16)(t[tx][ty + i] * sc);
  }
}

// ---------------- QKV GEMM: [8192,512] x [512,1536] -> Q/K [B,H,S,64], V^T [B,H,64,S]
__global__ __launch_bounds__(256) void gemm_qkv_kernel(
    const bf16* __restrict__ A,   // [8192][512]
    const bf16* __restrict__ Bt,  // [1536][512]  (w_qkv transposed)
    bf16* __restrict__ Qb, bf16* __restrict__ Kb, bf16* __restrict__ VT) {
  constexpr int K = 512;
  __shared__ __align__(16) bf16 As[128 * 32];
  __shared__ __align__(16) bf16 Bs[128 * 32];
  const int m0 = blockIdx.x * 128, n0 = blockIdx.y * 128;
  const int tid = threadIdx.x, lane = tid & 63, wave = tid >> 6;
  const int lr = lane & 15, lg = lane >> 4;
  const int wm = (wave >> 1) * 64, wn = (wave & 1) * 64;
  const int srow = wave * 16 + (lane >> 2);
  const int scol = (lane & 3) * 8;
  const bf16* ga = A  + (size_t)(m0 + srow) * K + scol;
  const bf16* gb = Bt + (size_t)(n0 + srow) * K + scol;
  bf16* lA = As + wave * 512;
  bf16* lB = Bs + wave * 512;
  f32x4 acc[4][4] = {};
  for (int k0 = 0; k0 < K; k0 += 32) {
    g2l_16(lA,        ga + k0);
    g2l_16(lA + 2048, ga + (size_t)64 * K + k0);
    g2l_16(lB,        gb + k0);
    g2l_16(lB + 2048, gb + (size_t)64 * K + k0);
    asm volatile("s_waitcnt vmcnt(0)" ::: "memory");
    __syncthreads();
    bf16x8 af[4], bfr[4];
#pragma unroll
    for (int i = 0; i < 4; ++i)
      af[i] = *(const bf16x8*)&As[(wm + i * 16 + lr) * 32 + lg * 8];
#pragma unroll
    for (int j = 0; j < 4; ++j)
      bfr[j] = *(const bf16x8*)&Bs[(wn + j * 16 + lr) * 32 + lg * 8];
#pragma unroll
    for (int i = 0; i < 4; ++i)
#pragma unroll
      for (int j = 0; j < 4; ++j)
        acc[i][j] = MFMA16(af[i], bfr[j], acc[i][j]);
    __syncthreads();
  }
#pragma unroll
  for (int j = 0; j < 4; ++j) {
    const int n = n0 + wn + j * 16 + lr;
    const int which = n >> 9, h = (n >> 6) & 7, dh = n & 63;
    if (which < 2) {
      bf16* dst = which == 0 ? Qb : Kb;
#pragma unroll
      for (int i = 0; i < 4; ++i)
#pragma unroll
        for (int r = 0; r < 4; ++r) {
          const int m = m0 + wm + i * 16 + lg * 4 + r;
          const int b = m >> 11, s2 = m & 2047;
          dst[((size_t)((b * Hh + h) * Seq + s2) << 6) | dh] = (bf16)acc[i][j][r];
        }
    } else {
      // V: write transposed [bh][dh][s]
#pragma unroll
      for (int i = 0; i < 4; ++i)
#pragma unroll
        for (int r = 0; r < 4; ++r) {
          const int m = m0 + wm + i * 16 + lg * 4 + r;
          const int b = m >> 11, s2 = m & 2047;
          VT[((size_t)((b * Hh + h) * Dh + dh)) * Seq + s2] = (bf16)acc[i][j][r];
        }
    }
  }
}

// ---------------- Out GEMM: [8192,512] x [512,512] + bias -> fp32 out --------------
__global__ __launch_bounds__(256) void gemm_out_kernel(
    const bf16* __restrict__ A,   // [8192][512] attention output
    const bf16* __restrict__ Bt,  // [512][512]  (w_out transposed)
    const float* __restrict__ bias, float* __restrict__ out) {
  constexpr int K = 512;
  __shared__ __align__(16) bf16 As[128 * 32];
  __shared__ __align__(16) bf16 Bs[128 * 32];
  const int m0 = blockIdx.x * 128, n0 = blockIdx.y * 128;
  const int tid = threadIdx.x, lane = tid & 63, wave = tid >> 6;
  const int lr = lane & 15, lg = lane >> 4;
  const int wm = (wave >> 1) * 64, wn = (wave & 1) * 64;
  const int srow = wave * 16 + (lane >> 2);
  const int scol = (lane & 3) * 8;
  const bf16* ga = A  + (size_t)(m0 + srow) * K + scol;
  const bf16* gb = Bt + (size_t)(n0 + srow) * K + scol;
  bf16* lA = As + wave * 512;
  bf16* lB = Bs + wave * 512;
  f32x4 acc[4][4] = {};
  for (int k0 = 0; k0 < K; k0 += 32) {
    g2l_16(lA,        ga + k0);
    g2l_16(lA + 2048, ga + (size_t)64 * K + k0);
    g2l_16(lB,        gb + k0);
    g2l_16(lB + 2048, gb + (size_t)64 * K + k0);
    asm volatile("s_waitcnt vmcnt(0)" ::: "memory");
    __syncthreads();
    bf16x8 af[4], bfr[4];
#pragma unroll
    for (int i = 0; i < 4; ++i)
      af[i] = *(const bf16x8*)&As[(wm + i * 16 + lr) * 32 + lg * 8];
#pragma unroll
    for (int j = 0; j < 4; ++j)
      bfr[j] = *(const bf16x8*)&Bs[(wn + j * 16 + lr) * 32 + lg * 8];
#pragma unroll
    for (int i = 0; i < 4; ++i)
#pragma unroll
      for (int j = 0; j < 4; ++j)
        acc[i][j] = MFMA16(af[i], bfr[j], acc[i][j]);
    __syncthreads();
  }
#pragma unroll
  for (int j = 0; j < 4; ++j) {
    const int n = n0 + wn + j * 16 + lr;
    const float bv = bias[n];
#pragma unroll
    for (int i = 0; i < 4; ++i)
#pragma unroll
      for (int r = 0; r < 4; ++r) {
        const int m = m0 + wm + i * 16 + lg * 4 + r;
        out[(size_t)m * 512 + n] = acc[i][j][r] + bv;
      }
  }
}

// ---- Flash attention v13: counted-vmcnt 3-buffer pipeline, margin-1 hardened ------
// 8 waves x 16 q (QBLK=128), KVBLK=64, 32 tiles. KV triple-buffered.
// Fences: leading = vmcnt(2) [buffer guaranteed one fence EARLY] + s_barrier +
// sched_barrier(0); trailing = lgkmcnt(0) + s_barrier + sched_barrier(0).
// Never drains vmcnt to 0 in the main loop (T4); margin-1 closes hoist races (r12).
__global__ __launch_bounds__(512) void attn13_kernel(
    const bf16* __restrict__ Qb, const bf16* __restrict__ Kb,
    const bf16* __restrict__ VT, bf16* __restrict__ A2) {
  // bijective XCD-chunked swizzle: 512 blocks -> 64/XCD -> 4 complete heads/XCD
  const int o   = blockIdx.x + gridDim.x * blockIdx.y;  // 0..511
  const int nid = ((o & 7) << 6) + (o >> 3);
  const int qc = nid & 15, bh = nid >> 4;
  const int b = bh >> 3, h = bh & 7;
  const int tid = threadIdx.x, lane = tid & 63, wave = tid >> 6;   // wave 0..7
  const int lr = lane & 15, lg = lane >> 4;
  const int q0 = qc * 128 + wave * 16;
  const bf16* Qh = Qb + (size_t)bh * Seq * Dh;
  const bf16* Kh = Kb + (size_t)bh * Seq * Dh;
  const bf16* Vh = VT + (size_t)bh * Dh * Seq;

  __shared__ __align__(16) bf16 KV[3][8192];
  __shared__ __align__(16) bf16 Pl[8][16][72];

  const int xs   = lr & 7;
  const int col0 = (lg ^ xs) * 8;
  const bf16* kv = &KV[0][0];
  const int kb0 = lr * 64 + col0;          // frag0 base
  const int kb1 = lr * 64 + (col0 ^ 32);   // frag1 base
  bf16* pw = &Pl[wave][lr][lg * 4];
  const bf16* pr = &Pl[wave][lr][lg * 8];

  const int krow = tid >> 3;                       // 0..63
  const int kc   = (((tid & 7) ^ (krow & 7)) * 8); // pre-swizzled source col
  const bf16* gK = Kh + (size_t)krow * 64 + kc;    // + t*4096
  const bf16* gV = Vh + (size_t)krow * Seq + kc;   // + t*64
  bf16* ldsD = &KV[0][0] + tid * 8;

  auto STAGE = [&](int dstOff, int t) {
    g2l_16(ldsD + dstOff,        gK + (size_t)t * 4096);
    g2l_16(ldsD + dstOff + 4096, gV + t * 64);
  };
  // leading fence: buffer for the upcoming TILE landed one fence ago (margin-1)
  auto FENCE_V2 = [&]() {
    asm volatile("s_waitcnt vmcnt(2)" ::: "memory");
    __builtin_amdgcn_s_barrier();
    __builtin_amdgcn_sched_barrier(0);
  };
  // trailing fence: all waves' DS ops drained before buffer overwrite (WAR)
  auto FENCE_WAR = [&]() {
    asm volatile("s_waitcnt lgkmcnt(0)" ::: "memory");
    __builtin_amdgcn_s_barrier();
    __builtin_amdgcn_sched_barrier(0);
  };

  bf16x8 qf0 = *(const bf16x8*)&Qh[(size_t)(q0 + lr) * 64 + lg * 8];
  bf16x8 qf1 = *(const bf16x8*)&Qh[(size_t)(q0 + lr) * 64 + 32 + lg * 8];

  f32x4 oa[4] = {};
  f32x4 ol = {};                     // ol[j] = running row-sum l for q = q0+4lg+j
  float m = -1e30f;
  bf16x8 ones;
#pragma unroll
  for (int i = 0; i < 8; ++i) ones[i] = (bf16)1.0f;

  auto TILE = [&](int buf) {   // buf is a literal at every call site
    const int kB = buf * 8192;
    // S^T = K Q'^T  (Q pre-scaled by 64^-0.5*log2e at weight-cast time)
    f32x4 st[4] = {};
#pragma unroll
    for (int c = 0; c < 4; ++c) {
      bf16x8 kf0 = *(const bf16x8*)&kv[kb0 + kB + c * 1024];
      bf16x8 kf1 = *(const bf16x8*)&kv[kb1 + kB + c * 1024];
      st[c] = MFMA16(kf0, qf0, st[c]);
      st[c] = MFMA16(kf1, qf1, st[c]);
    }
    // online softmax: max3 tree + 2 shuffles; defer-max THR=3 (exp2 domain)
    float m0 = max3f(st[0][0], st[0][1], st[0][2]);
    float m1 = max3f(st[0][3], st[1][0], st[1][1]);
    float m2 = max3f(st[1][2], st[1][3], st[2][0]);
    float m3 = max3f(st[2][1], st[2][2], st[2][3]);
    float m4 = max3f(st[3][0], st[3][1], st[3][2]);
    float mx = max3f(max3f(m0, m1, m2), m3, fmaxf(m4, st[3][3]));
    mx = fmaxf(mx, __shfl_xor(mx, 16));
    mx = fmaxf(mx, __shfl_xor(mx, 32));
    if (__any(mx > m + 3.0f)) {
      const float mn = fmaxf(m, mx);
      const float al = exp2f(m - mn);
      m = mn;
#pragma unroll
      for (int j = 0; j < 4; ++j) {
        const float aj = __shfl(al, lg * 4 + j);
        ol[j] *= aj;
#pragma unroll
        for (int n = 0; n < 4; ++n) oa[n][j] *= aj;
      }
    }
#pragma unroll
    for (int c = 0; c < 4; ++c) {
      bf16x4 pk;
#pragma unroll
      for (int j = 0; j < 4; ++j) pk[j] = (bf16)exp2f(st[c][j] - m);
      *(bf16x4*)&pw[c * 16] = pk;          // imm offset c*32 bytes
    }
    // PV + ones-MFMA row-sum
    bf16x8 pf0 = *(const bf16x8*)&pr[0];
    bf16x8 pf1 = *(const bf16x8*)&pr[32];
    ol = MFMA16(pf0, ones, ol);
    ol = MFMA16(pf1, ones, ol);
#pragma unroll
    for (int n = 0; n < 4; ++n) {
      bf16x8 vf0 = *(const bf16x8*)&kv[kb0 + kB + 4096 + n * 1024];
      bf16x8 vf1 = *(const bf16x8*)&kv[kb1 + kB + 4096 + n * 1024];
      oa[n] = MFMA16(pf0, vf0, oa[n]);
      oa[n] = MFMA16(pf1, vf1, oa[n]);
    }
  };

  // prologue: stage tiles 0,1 (4 loads in flight)
  STAGE(0, 0);
  STAGE(8192, 1);

  for (int k = 0; k < 10; ++k) {
    const int t = k * 3;
    STAGE(16384, t + 2);   // buf2 <- tile t+2
    FENCE_V2();            // tiles t AND t+1 landed (margin-1 for TILE(0))
    TILE(0);
    FENCE_WAR();           // all waves done reading buf0
    STAGE(0, t + 3);       // buf0 <- tile t+3
    FENCE_V2();            // tile t+2 landed (margin-1 for TILE(1))
    TILE(1);
    FENCE_WAR();
    STAGE(8192, t + 4);    // buf1 <- tile t+4
    FENCE_V2();            // tile t+3 landed (margin-1 for TILE(2))
    TILE(2);
    FENCE_WAR();
  }
  // tail: tiles 30 (buf0), 31 (buf1); drain fully (2 tiles, negligible cost)
  asm volatile("s_waitcnt vmcnt(0)" ::: "memory");
  __builtin_amdgcn_s_barrier();
  __builtin_amdgcn_sched_barrier(0);
  TILE(0);
  FENCE_WAR();
  TILE(1);

  // epilogue: normalize (l held in-lane), write [B*S, 512] bf16
#pragma unroll
  for (int j = 0; j < 4; ++j) {
    const float lj = 1.0f / ol[j];
    const int s2 = q0 + lg * 4 + j;
#pragma unroll
    for (int n = 0; n < 4; ++n)
      A2[(size_t)(b * Seq + s2) * 512 + h * 64 + n * 16 + lr] = (bf16)(oa[n][j] * lj);
  }
}

extern "C" void kernel_launch(void* const* d_in, const int* in_sizes, int n_in,
                              void* d_out, int out_size, void* d_ws, size_t ws_size,
                              hipStream_t stream) {
  const float* x    = (const float*)d_in[0];
  const float* gam  = (const float*)d_in[1];
  const float* bet  = (const float*)d_in[2];
  const float* wqkv = (const float*)d_in[3];  // [512][1536]
  const float* wout = (const float*)d_in[4];  // [512][512]
  const float* bout = (const float*)d_in[5];  // [512]
  float* out = (float*)d_out;

  bf16* xn    = (bf16*)d_ws;                        // [8192][512]   8 MB
  bf16* wqkvT = xn    + (size_t)8192 * 512;         // [1536][512]   1.5 MB
  bf16* woutT = wqkvT + (size_t)1536 * 512;         // [512][512]    0.5 MB
  bf16* Qb    = woutT + (size_t)512 * 512;          // [4,8,2048,64] 8 MB
  bf16* Kb    = Qb    + (size_t)4 * 8 * 2048 * 64;
  bf16* VT    = Kb    + (size_t)4 * 8 * 2048 * 64;  // [4,8,64,2048] 8 MB
  bf16* A2    = xn;  // reuse: xn dead after QKV GEMM

  // 64^-0.5 * log2(e) folded into Q columns of w_qkv
  const float K1 = 0.18033688011112042f;

  ln_cast_kernel<<<2048, 256, 0, stream>>>(x, gam, bet, xn);
  tcast_kernel<<<dim3(48, 16), 256, 0, stream>>>(wqkv, wqkvT, 512, 1536, 512, K1);
  tcast_kernel<<<dim3(16, 16), 256, 0, stream>>>(wout, woutT, 512, 512, 0, 1.0f);
  gemm_qkv_kernel<<<dim3(64, 12), 256, 0, stream>>>(xn, wqkvT, Qb, Kb, VT);
  attn13_kernel<<<dim3(16, 32), 512, 0, stream>>>(Qb, Kb, VT, A2);
  gemm_out_kernel<<<dim3(64, 4), 256, 0, stream>>>(A2, woutT, bout, out);
}